// Round 1
// baseline (420.011 us; speedup 1.0000x reference)
//
#include <hip/hip_runtime.h>
#include <hip/hip_bf16.h>
#include <cmath>

typedef __bf16 bf16;
typedef __bf16 bf16x8 __attribute__((ext_vector_type(8)));
typedef __bf16 bf16x4 __attribute__((ext_vector_type(4)));
typedef float  f32x4  __attribute__((ext_vector_type(4)));

#define B_   2
#define T_   2048
#define D_   1024
#define H_   16
#define DH_  64
#define BT_  (B_ * T_)     // 4096
#define DFF_ (4 * D_)      // 4096

// ---------------- fp32 -> bf16 convert, 4 elems/thread ----------------
__global__ void cvt_f32_bf16(const float* __restrict__ src, bf16* __restrict__ dst, int n) {
    int i = (blockIdx.x * blockDim.x + threadIdx.x) * 4;
    if (i >= n) return;
    float4 v = *(const float4*)(src + i);
    bf16x4 o;
    o[0] = (bf16)v.x; o[1] = (bf16)v.y; o[2] = (bf16)v.z; o[3] = (bf16)v.w;
    *(bf16x4*)(dst + i) = o;
}

__device__ __forceinline__ float gelu_f(float v) {
    return 0.5f * v * (1.0f + erff(v * 0.70710678118654752f));
}

// ---------------- GEMM: C[M,N] = A[M,K] * Bt[N,K]^T  (m97-style 128x128 tile) ----
// EPI 0: bf16 out plain; EPI 1: bf16 out = gelu(acc + bias); EPI 2: f32 out = acc + bias + resid
template <int EPI>
__global__ __launch_bounds__(256) void gemm_bt(
    const bf16* __restrict__ A, const bf16* __restrict__ Bt,
    void* __restrict__ outp, const float* __restrict__ bias,
    const float* __restrict__ resid, int M, int N, int K)
{
    __shared__ __align__(16) bf16 As[128 * 32];
    __shared__ __align__(16) bf16 Bs[128 * 32];
    const int tid  = threadIdx.x;
    const int lane = tid & 63;
    const int w    = tid >> 6;
    const int wr   = w >> 1, wc = w & 1;
    const int g    = lane >> 4, cc = lane & 15;
    const int m0   = blockIdx.y * 128, n0 = blockIdx.x * 128;

    f32x4 acc[4][4] = {};

    // staging: 512 chunks of 16B per tile (A and B). thread t takes chunks t and t+256.
    const int c0 = tid, c1 = tid + 256;
    const bf16* gA0 = A  + (long)(m0 + (c0 >> 2)) * K + ((c0 & 3) << 3);
    const bf16* gA1 = A  + (long)(m0 + (c1 >> 2)) * K + ((c1 & 3) << 3);
    const bf16* gB0 = Bt + (long)(n0 + (c0 >> 2)) * K + ((c0 & 3) << 3);
    const bf16* gB1 = Bt + (long)(n0 + (c1 >> 2)) * K + ((c1 & 3) << 3);
    bf16* lA0 = As + c0 * 8;
    bf16* lA1 = As + c1 * 8;
    bf16* lB0 = Bs + c0 * 8;
    bf16* lB1 = Bs + c1 * 8;

    for (int k0 = 0; k0 < K; k0 += 32) {
        __builtin_amdgcn_global_load_lds((const __attribute__((address_space(1))) void*)(gA0 + k0),
                                         (__attribute__((address_space(3))) void*)lA0, 16, 0, 0);
        __builtin_amdgcn_global_load_lds((const __attribute__((address_space(1))) void*)(gA1 + k0),
                                         (__attribute__((address_space(3))) void*)lA1, 16, 0, 0);
        __builtin_amdgcn_global_load_lds((const __attribute__((address_space(1))) void*)(gB0 + k0),
                                         (__attribute__((address_space(3))) void*)lB0, 16, 0, 0);
        __builtin_amdgcn_global_load_lds((const __attribute__((address_space(1))) void*)(gB1 + k0),
                                         (__attribute__((address_space(3))) void*)lB1, 16, 0, 0);
        __syncthreads();   // compiler emits vmcnt(0) drain before barrier -> LDS ready

        bf16x8 af[4], bfr[4];
        #pragma unroll
        for (int mi = 0; mi < 4; mi++)
            af[mi] = *(const bf16x8*)&As[(wr * 64 + mi * 16 + cc) * 32 + g * 8];
        #pragma unroll
        for (int ni = 0; ni < 4; ni++)
            bfr[ni] = *(const bf16x8*)&Bs[(wc * 64 + ni * 16 + cc) * 32 + g * 8];
        #pragma unroll
        for (int mi = 0; mi < 4; mi++)
            #pragma unroll
            for (int ni = 0; ni < 4; ni++)
                acc[mi][ni] = __builtin_amdgcn_mfma_f32_16x16x32_bf16(af[mi], bfr[ni], acc[mi][ni], 0, 0, 0);
        __syncthreads();   // protect LDS before next stage overwrites
    }

    // epilogue: C row = m0+wr*64+mi*16+4*g+r, col = n0+wc*64+ni*16+cc
    #pragma unroll
    for (int mi = 0; mi < 4; mi++) {
        #pragma unroll
        for (int ni = 0; ni < 4; ni++) {
            #pragma unroll
            for (int r = 0; r < 4; r++) {
                int grow = m0 + wr * 64 + mi * 16 + g * 4 + r;
                int gcol = n0 + wc * 64 + ni * 16 + cc;
                float v = acc[mi][ni][r];
                if constexpr (EPI == 0) {
                    ((bf16*)outp)[(long)grow * N + gcol] = (bf16)v;
                } else if constexpr (EPI == 1) {
                    v += bias[gcol];
                    ((bf16*)outp)[(long)grow * N + gcol] = (bf16)gelu_f(v);
                } else {
                    v += bias[gcol] + resid[(long)grow * N + gcol];
                    ((float*)outp)[(long)grow * N + gcol] = v;
                }
            }
        }
    }
}

// ---------------- flash attention, causal. 1 wave per (b, h, 16 q-rows) ------------
// qkv: [BT, 3*D] bf16 (cols 0:1024 Q, 1024:2048 K, 2048:3072 V, per-head 64-wide slices)
// h_out[bt, d] = x[bt, d] + attn_out
__global__ __launch_bounds__(64) void attn_kernel(
    const bf16* __restrict__ qkv, const float* __restrict__ x,
    bf16* __restrict__ hout)
{
    const int lane = threadIdx.x & 63;
    const int g = lane >> 4, cc = lane & 15;
    const int qt = blockIdx.x, hh = blockIdx.y, b = blockIdx.z;
    const int qbase = qt * 16;
    __shared__ __align__(16) bf16 P_lds[16][32];

    const long rowQ = (long)(b * T_ + qbase + cc) * (3 * D_) + hh * 64;
    bf16x8 qf0 = *(const bf16x8*)&qkv[rowQ + g * 8];
    bf16x8 qf1 = *(const bf16x8*)&qkv[rowQ + 32 + g * 8];

    float m_run[4] = {-INFINITY, -INFINITY, -INFINITY, -INFINITY};
    float l_run[4] = {0.f, 0.f, 0.f, 0.f};
    f32x4 o_acc[4] = {};

    for (int kv0 = 0; kv0 < qbase + 16; kv0 += 32) {
        // S[16q, 32kv] via 2 half-tiles
        f32x4 s[2];
        #pragma unroll
        for (int half = 0; half < 2; half++) {
            const long rowK = (long)(b * T_ + kv0 + half * 16 + cc) * (3 * D_) + D_ + hh * 64;
            bf16x8 kf0 = *(const bf16x8*)&qkv[rowK + g * 8];
            bf16x8 kf1 = *(const bf16x8*)&qkv[rowK + 32 + g * 8];
            f32x4 sa = {};
            sa = __builtin_amdgcn_mfma_f32_16x16x32_bf16(qf0, kf0, sa, 0, 0, 0);
            sa = __builtin_amdgcn_mfma_f32_16x16x32_bf16(qf1, kf1, sa, 0, 0, 0);
            s[half] = sa;
        }
        // scale + causal mask + row max
        float pmax[4];
        #pragma unroll
        for (int r = 0; r < 4; r++) {
            int q = qbase + 4 * g + r;
            float v0 = s[0][r] * 0.125f; if (kv0 + cc      > q) v0 = -INFINITY;
            float v1 = s[1][r] * 0.125f; if (kv0 + 16 + cc > q) v1 = -INFINITY;
            s[0][r] = v0; s[1][r] = v1;
            pmax[r] = fmaxf(v0, v1);
        }
        #pragma unroll
        for (int mk = 1; mk < 16; mk <<= 1)
            #pragma unroll
            for (int r = 0; r < 4; r++)
                pmax[r] = fmaxf(pmax[r], __shfl_xor(pmax[r], mk));

        float alpha[4], rs[4];
        #pragma unroll
        for (int r = 0; r < 4; r++) {
            float mn = fmaxf(m_run[r], pmax[r]);
            alpha[r] = expf(m_run[r] - mn);
            m_run[r] = mn;
            float p0 = expf(s[0][r] - mn);
            float p1 = expf(s[1][r] - mn);
            s[0][r] = p0; s[1][r] = p1;
            rs[r] = p0 + p1;
        }
        #pragma unroll
        for (int mk = 1; mk < 16; mk <<= 1)
            #pragma unroll
            for (int r = 0; r < 4; r++)
                rs[r] += __shfl_xor(rs[r], mk);
        #pragma unroll
        for (int r = 0; r < 4; r++) l_run[r] = l_run[r] * alpha[r] + rs[r];
        #pragma unroll
        for (int ec = 0; ec < 4; ec++)
            #pragma unroll
            for (int r = 0; r < 4; r++) o_acc[ec][r] *= alpha[r];

        // P: C-layout -> LDS -> A-layout
        __syncthreads();
        #pragma unroll
        for (int r = 0; r < 4; r++) {
            P_lds[4 * g + r][cc]      = (bf16)s[0][r];
            P_lds[4 * g + r][16 + cc] = (bf16)s[1][r];
        }
        __syncthreads();
        bf16x8 pf = *(const bf16x8*)&P_lds[cc][g * 8];

        // PV: O[16q, 64e] += P[16,32] * V[32,64]
        const long rowV = (long)(b * T_ + kv0 + g * 8) * (3 * D_) + 2 * D_ + hh * 64;
        #pragma unroll
        for (int ec = 0; ec < 4; ec++) {
            bf16x8 vf;
            #pragma unroll
            for (int i = 0; i < 8; i++)
                vf[i] = qkv[rowV + (long)i * (3 * D_) + ec * 16 + cc];
            o_acc[ec] = __builtin_amdgcn_mfma_f32_16x16x32_bf16(pf, vf, o_acc[ec], 0, 0, 0);
        }
    }

    #pragma unroll
    for (int ec = 0; ec < 4; ec++) {
        #pragma unroll
        for (int r = 0; r < 4; r++) {
            long idx = (long)(b * T_ + qbase + 4 * g + r) * D_ + hh * 64 + ec * 16 + cc;
            hout[idx] = (bf16)(x[idx] + o_acc[ec][r] / l_run[r]);
        }
    }
}

// ---------------- launch ----------------
extern "C" void kernel_launch(void* const* d_in, const int* in_sizes, int n_in,
                              void* d_out, int out_size, void* d_ws, size_t ws_size,
                              hipStream_t stream) {
    const float* x  = (const float*)d_in[0];
    // d_in[1] = mask (causal, implicit)
    const float* wq = (const float*)d_in[2];
    const float* wk = (const float*)d_in[3];
    const float* wv = (const float*)d_in[4];
    const float* w1 = (const float*)d_in[5];
    const float* b1 = (const float*)d_in[6];
    const float* w2 = (const float*)d_in[7];
    const float* b2 = (const float*)d_in[8];
    float* out = (float*)d_out;

    char* ws = (char*)d_ws;
    bf16* xb   = (bf16*)(ws);                  // [4096,1024]   8 MB
    bf16* wall = (bf16*)(ws + (8L  << 20));    // [3072,1024]   6 MB  (wq|wk|wv rows)
    bf16* w1b  = (bf16*)(ws + (14L << 20));    // [4096,1024]   8 MB
    bf16* w2b  = (bf16*)(ws + (22L << 20));    // [1024,4096]   8 MB
    bf16* qkv  = (bf16*)(ws + (30L << 20));    // [4096,3072]  24 MB
    bf16* hbuf = (bf16*)(ws + (54L << 20));    // [4096,1024]   8 MB
    bf16* abuf = (bf16*)(ws + (62L << 20));    // [4096,4096]  32 MB

    auto cvt = [&](const float* s, bf16* d, int n) {
        cvt_f32_bf16<<<(n / 4 + 255) / 256, 256, 0, stream>>>(s, d, n);
    };
    cvt(x,  xb,              BT_ * D_);
    cvt(wq, wall,            D_ * D_);
    cvt(wk, wall + D_ * D_,  D_ * D_);
    cvt(wv, wall + 2 * D_ * D_, D_ * D_);
    cvt(w1, w1b, DFF_ * D_);
    cvt(w2, w2b, D_ * DFF_);

    // QKV projection: [4096,1024] x [3072,1024]^T -> [4096,3072]
    gemm_bt<0><<<dim3(3 * D_ / 128, BT_ / 128), 256, 0, stream>>>(
        xb, wall, qkv, nullptr, nullptr, BT_, 3 * D_, D_);

    // attention + residual: hbuf = x + attn_out
    attn_kernel<<<dim3(T_ / 16, H_, B_), 64, 0, stream>>>(qkv, x, hbuf);

    // FFN1: gelu(h @ w1^T + b1) -> [4096,4096] bf16
    gemm_bt<1><<<dim3(DFF_ / 128, BT_ / 128), 256, 0, stream>>>(
        hbuf, w1b, abuf, b1, nullptr, BT_, DFF_, D_);

    // FFN2 + bias + residual x -> out fp32 [4096,1024]
    gemm_bt<2><<<dim3(D_ / 128, BT_ / 128), 256, 0, stream>>>(
        abuf, w2b, out, b2, x, BT_, D_, DFF_);
}

// Round 2
// 337.869 us; speedup vs baseline: 1.2431x; 1.2431x over previous
//
#include <hip/hip_runtime.h>
#include <hip/hip_bf16.h>
#include <cmath>

typedef __bf16 bf16;
typedef __bf16 bf16x8 __attribute__((ext_vector_type(8)));
typedef __bf16 bf16x4 __attribute__((ext_vector_type(4)));
typedef float  f32x4  __attribute__((ext_vector_type(4)));

#define B_   2
#define T_   2048
#define D_   1024
#define H_   16
#define DH_  64
#define BT_  (B_ * T_)     // 4096
#define DFF_ (4 * D_)      // 4096

// ---------------- fp32 -> bf16 convert, 4 elems/thread ----------------
__global__ void cvt_f32_bf16(const float* __restrict__ src, bf16* __restrict__ dst, int n) {
    int i = (blockIdx.x * blockDim.x + threadIdx.x) * 4;
    if (i >= n) return;
    float4 v = *(const float4*)(src + i);
    bf16x4 o;
    o[0] = (bf16)v.x; o[1] = (bf16)v.y; o[2] = (bf16)v.z; o[3] = (bf16)v.w;
    *(bf16x4*)(dst + i) = o;
}

__device__ __forceinline__ float gelu_f(float v) {
    return 0.5f * v * (1.0f + erff(v * 0.70710678118654752f));
}

// ---------------- GEMM: C[M,N] = A[M,K] * Bt[N,K]^T  (m97-style 128x128 tile) ----
// EPI 1: bf16 out = gelu(acc + bias); EPI 2: f32 out = acc + bias + resid
// EPI 3: QKV split: cols < 2048 -> qk rowmajor [M][2048]; cols >= 2048 -> vt [B][1024][T] (transposed)
template <int EPI>
__global__ __launch_bounds__(256) void gemm_bt(
    const bf16* __restrict__ A, const bf16* __restrict__ Bt,
    void* __restrict__ outp, void* __restrict__ outp2, const float* __restrict__ bias,
    const float* __restrict__ resid, int M, int N, int K)
{
    __shared__ __align__(16) bf16 As[128 * 32];
    __shared__ __align__(16) bf16 Bs[128 * 32];
    const int tid  = threadIdx.x;
    const int lane = tid & 63;
    const int w    = tid >> 6;
    const int wr   = w >> 1, wc = w & 1;
    const int g    = lane >> 4, cc = lane & 15;
    const int m0   = blockIdx.y * 128, n0 = blockIdx.x * 128;

    f32x4 acc[4][4] = {};

    const int c0 = tid, c1 = tid + 256;
    const bf16* gA0 = A  + (long)(m0 + (c0 >> 2)) * K + ((c0 & 3) << 3);
    const bf16* gA1 = A  + (long)(m0 + (c1 >> 2)) * K + ((c1 & 3) << 3);
    const bf16* gB0 = Bt + (long)(n0 + (c0 >> 2)) * K + ((c0 & 3) << 3);
    const bf16* gB1 = Bt + (long)(n0 + (c1 >> 2)) * K + ((c1 & 3) << 3);
    bf16* lA0 = As + c0 * 8;
    bf16* lA1 = As + c1 * 8;
    bf16* lB0 = Bs + c0 * 8;
    bf16* lB1 = Bs + c1 * 8;

    for (int k0 = 0; k0 < K; k0 += 32) {
        __builtin_amdgcn_global_load_lds((const __attribute__((address_space(1))) void*)(gA0 + k0),
                                         (__attribute__((address_space(3))) void*)lA0, 16, 0, 0);
        __builtin_amdgcn_global_load_lds((const __attribute__((address_space(1))) void*)(gA1 + k0),
                                         (__attribute__((address_space(3))) void*)lA1, 16, 0, 0);
        __builtin_amdgcn_global_load_lds((const __attribute__((address_space(1))) void*)(gB0 + k0),
                                         (__attribute__((address_space(3))) void*)lB0, 16, 0, 0);
        __builtin_amdgcn_global_load_lds((const __attribute__((address_space(1))) void*)(gB1 + k0),
                                         (__attribute__((address_space(3))) void*)lB1, 16, 0, 0);
        __syncthreads();

        bf16x8 af[4], bfr[4];
        #pragma unroll
        for (int mi = 0; mi < 4; mi++)
            af[mi] = *(const bf16x8*)&As[(wr * 64 + mi * 16 + cc) * 32 + g * 8];
        #pragma unroll
        for (int ni = 0; ni < 4; ni++)
            bfr[ni] = *(const bf16x8*)&Bs[(wc * 64 + ni * 16 + cc) * 32 + g * 8];
        #pragma unroll
        for (int mi = 0; mi < 4; mi++)
            #pragma unroll
            for (int ni = 0; ni < 4; ni++)
                acc[mi][ni] = __builtin_amdgcn_mfma_f32_16x16x32_bf16(af[mi], bfr[ni], acc[mi][ni], 0, 0, 0);
        __syncthreads();
    }

    if constexpr (EPI == 3) {
        if (n0 >= 2048) {
            // V part -> transposed layout vt[b][e][t]
            #pragma unroll
            for (int mi = 0; mi < 4; mi++) {
                #pragma unroll
                for (int ni = 0; ni < 4; ni++) {
                    int gcol  = n0 + wc * 64 + ni * 16 + cc - 2048;
                    int grow0 = m0 + wr * 64 + mi * 16 + g * 4;
                    int bb = grow0 >> 11, t = grow0 & 2047;
                    bf16x4 o;
                    #pragma unroll
                    for (int r = 0; r < 4; r++) o[r] = (bf16)acc[mi][ni][r];
                    *(bf16x4*)&((bf16*)outp2)[((long)bb * 1024 + gcol) * 2048 + t] = o;
                }
            }
        } else {
            #pragma unroll
            for (int mi = 0; mi < 4; mi++)
                #pragma unroll
                for (int ni = 0; ni < 4; ni++)
                    #pragma unroll
                    for (int r = 0; r < 4; r++) {
                        int grow = m0 + wr * 64 + mi * 16 + g * 4 + r;
                        int gcol = n0 + wc * 64 + ni * 16 + cc;
                        ((bf16*)outp)[(long)grow * 2048 + gcol] = (bf16)acc[mi][ni][r];
                    }
        }
        return;
    }

    #pragma unroll
    for (int mi = 0; mi < 4; mi++) {
        #pragma unroll
        for (int ni = 0; ni < 4; ni++) {
            #pragma unroll
            for (int r = 0; r < 4; r++) {
                int grow = m0 + wr * 64 + mi * 16 + g * 4 + r;
                int gcol = n0 + wc * 64 + ni * 16 + cc;
                float v = acc[mi][ni][r];
                if constexpr (EPI == 1) {
                    v += bias[gcol];
                    ((bf16*)outp)[(long)grow * N + gcol] = (bf16)gelu_f(v);
                } else {
                    v += bias[gcol] + resid[(long)grow * N + gcol];
                    ((float*)outp)[(long)grow * N + gcol] = v;
                }
            }
        }
    }
}

// ---------------- flash attention v2: 4 waves/block, 64 q rows, LDS K/V tiles -----
// qk: [BT][2048] bf16 (Q cols 0:1024, K cols 1024:2048, per-head 64-wide)
// vt: [B][1024][T] bf16 (V transposed: vt[b][h*64+e][t])
// hout[bt,d] = x[bt,d] + attn_out
__global__ __launch_bounds__(256) void attn_kernel(
    const bf16* __restrict__ qk, const bf16* __restrict__ vt,
    const float* __restrict__ x, bf16* __restrict__ hout)
{
    __shared__ __align__(16) bf16 Ks[64 * 64];
    __shared__ __align__(16) bf16 Vs[64 * 64];
    __shared__ __align__(16) bf16 Ps[4][16 * 64];
    const int tid  = threadIdx.x;
    const int lane = tid & 63, w = tid >> 6;
    const int g = lane >> 4, cc = lane & 15;
    const int qt = gridDim.x - 1 - blockIdx.x;   // heavy blocks first
    const int hh = blockIdx.y, b = blockIdx.z;
    const int qbase = qt * 64;

    const bf16* qkb   = qk + (long)b * T_ * 2048;
    const bf16* kbase = qkb + 1024 + hh * 64;
    const bf16* vbase = vt + ((long)b * 1024 + hh * 64) * 2048;

    // Q fragments: wave's 16 q rows (row = cc), k = e
    const long rowQ = (long)(qbase + w * 16 + cc) * 2048 + hh * 64;
    bf16x8 qf0 = *(const bf16x8*)&qkb[rowQ + g * 8];
    bf16x8 qf1 = *(const bf16x8*)&qkb[rowQ + 32 + g * 8];

    float m_run[4] = {-INFINITY, -INFINITY, -INFINITY, -INFINITY};
    float l_run[4] = {0.f, 0.f, 0.f, 0.f};
    f32x4 o_acc[4] = {};

    // staging chunk decomposition: 512 chunks of 16B each for K and V
    const int c0 = tid, c1 = tid + 256;
    const int r0 = c0 >> 3, s0 = ((c0 & 7) ^ (r0 & 7)) << 3;  // swizzled src elem offset
    const int r1 = c1 >> 3, s1 = ((c1 & 7) ^ (r1 & 7)) << 3;
    const int x7 = cc & 7;  // read-side XOR key

    for (int kv0 = 0; kv0 <= qbase; kv0 += 64) {
        __builtin_amdgcn_global_load_lds(
            (const __attribute__((address_space(1))) void*)(kbase + (long)(kv0 + r0) * 2048 + s0),
            (__attribute__((address_space(3))) void*)(Ks + c0 * 8), 16, 0, 0);
        __builtin_amdgcn_global_load_lds(
            (const __attribute__((address_space(1))) void*)(kbase + (long)(kv0 + r1) * 2048 + s1),
            (__attribute__((address_space(3))) void*)(Ks + c1 * 8), 16, 0, 0);
        __builtin_amdgcn_global_load_lds(
            (const __attribute__((address_space(1))) void*)(vbase + (long)r0 * 2048 + kv0 + s0),
            (__attribute__((address_space(3))) void*)(Vs + c0 * 8), 16, 0, 0);
        __builtin_amdgcn_global_load_lds(
            (const __attribute__((address_space(1))) void*)(vbase + (long)r1 * 2048 + kv0 + s1),
            (__attribute__((address_space(3))) void*)(Vs + c1 * 8), 16, 0, 0);
        __syncthreads();

        // ---- S[16q x 64kv] = Q K^T ----
        f32x4 sacc[4] = {};
        #pragma unroll
        for (int kt = 0; kt < 4; kt++) {
            bf16x8 kf0 = *(const bf16x8*)&Ks[(kt * 16 + cc) * 64 + ((g ^ x7) << 3)];
            bf16x8 kf1 = *(const bf16x8*)&Ks[(kt * 16 + cc) * 64 + (((4 | g) ^ x7) << 3)];
            sacc[kt] = __builtin_amdgcn_mfma_f32_16x16x32_bf16(qf0, kf0, sacc[kt], 0, 0, 0);
            sacc[kt] = __builtin_amdgcn_mfma_f32_16x16x32_bf16(qf1, kf1, sacc[kt], 0, 0, 0);
        }

        // ---- online softmax ----
        float pmax[4];
        #pragma unroll
        for (int r = 0; r < 4; r++) {
            float a0 = sacc[0][r] * 0.125f, a1 = sacc[1][r] * 0.125f;
            float a2 = sacc[2][r] * 0.125f, a3 = sacc[3][r] * 0.125f;
            if (kv0 == qbase) {  // diagonal tile: mask kv > q (block-relative)
                int q = w * 16 + 4 * g + r;
                if (cc      > q) a0 = -INFINITY;
                if (16 + cc > q) a1 = -INFINITY;
                if (32 + cc > q) a2 = -INFINITY;
                if (48 + cc > q) a3 = -INFINITY;
            }
            sacc[0][r] = a0; sacc[1][r] = a1; sacc[2][r] = a2; sacc[3][r] = a3;
            pmax[r] = fmaxf(fmaxf(a0, a1), fmaxf(a2, a3));
        }
        #pragma unroll
        for (int mk = 1; mk < 16; mk <<= 1)
            #pragma unroll
            for (int r = 0; r < 4; r++)
                pmax[r] = fmaxf(pmax[r], __shfl_xor(pmax[r], mk));

        float alpha[4], rs[4];
        #pragma unroll
        for (int r = 0; r < 4; r++) {
            float mn = fmaxf(m_run[r], pmax[r]);
            alpha[r] = __expf(m_run[r] - mn);
            m_run[r] = mn;
            float p0 = __expf(sacc[0][r] - mn);
            float p1 = __expf(sacc[1][r] - mn);
            float p2 = __expf(sacc[2][r] - mn);
            float p3 = __expf(sacc[3][r] - mn);
            sacc[0][r] = p0; sacc[1][r] = p1; sacc[2][r] = p2; sacc[3][r] = p3;
            rs[r] = (p0 + p1) + (p2 + p3);
        }
        #pragma unroll
        for (int mk = 1; mk < 16; mk <<= 1)
            #pragma unroll
            for (int r = 0; r < 4; r++)
                rs[r] += __shfl_xor(rs[r], mk);
        #pragma unroll
        for (int r = 0; r < 4; r++) l_run[r] = l_run[r] * alpha[r] + rs[r];
        #pragma unroll
        for (int ec = 0; ec < 4; ec++)
            #pragma unroll
            for (int r = 0; r < 4; r++) o_acc[ec][r] *= alpha[r];

        // ---- P: C-layout -> per-wave swizzled LDS -> A-frag ----
        #pragma unroll
        for (int r = 0; r < 4; r++) {
            int qr = 4 * g + r;
            #pragma unroll
            for (int kt = 0; kt < 4; kt++) {
                int seg = (kt << 1) | (cc >> 3);
                Ps[w][qr * 64 + (((seg ^ (qr & 7)) << 3) | x7)] = (bf16)sacc[kt][r];
            }
        }
        bf16x8 pf0 = *(const bf16x8*)&Ps[w][cc * 64 + ((g ^ x7) << 3)];
        bf16x8 pf1 = *(const bf16x8*)&Ps[w][cc * 64 + (((4 | g) ^ x7) << 3)];

        // ---- O += P V ----
        #pragma unroll
        for (int ec = 0; ec < 4; ec++) {
            bf16x8 vf0 = *(const bf16x8*)&Vs[(ec * 16 + cc) * 64 + ((g ^ x7) << 3)];
            bf16x8 vf1 = *(const bf16x8*)&Vs[(ec * 16 + cc) * 64 + (((4 | g) ^ x7) << 3)];
            o_acc[ec] = __builtin_amdgcn_mfma_f32_16x16x32_bf16(pf0, vf0, o_acc[ec], 0, 0, 0);
            o_acc[ec] = __builtin_amdgcn_mfma_f32_16x16x32_bf16(pf1, vf1, o_acc[ec], 0, 0, 0);
        }
        __syncthreads();
    }

    #pragma unroll
    for (int ec = 0; ec < 4; ec++) {
        #pragma unroll
        for (int r = 0; r < 4; r++) {
            long idx = (long)(b * T_ + qbase + w * 16 + 4 * g + r) * D_ + hh * 64 + ec * 16 + cc;
            hout[idx] = (bf16)(x[idx] + o_acc[ec][r] / l_run[r]);
        }
    }
}

// ---------------- launch ----------------
extern "C" void kernel_launch(void* const* d_in, const int* in_sizes, int n_in,
                              void* d_out, int out_size, void* d_ws, size_t ws_size,
                              hipStream_t stream) {
    const float* x  = (const float*)d_in[0];
    // d_in[1] = mask (causal, implicit)
    const float* wq = (const float*)d_in[2];
    const float* wk = (const float*)d_in[3];
    const float* wv = (const float*)d_in[4];
    const float* w1 = (const float*)d_in[5];
    const float* b1 = (const float*)d_in[6];
    const float* w2 = (const float*)d_in[7];
    const float* b2 = (const float*)d_in[8];
    float* out = (float*)d_out;

    char* ws = (char*)d_ws;
    bf16* xb   = (bf16*)(ws);                  // [4096,1024]   8 MB
    bf16* wall = (bf16*)(ws + (8L  << 20));    // [3072,1024]   6 MB  (wq|wk|wv rows)
    bf16* w1b  = (bf16*)(ws + (14L << 20));    // [4096,1024]   8 MB
    bf16* w2b  = (bf16*)(ws + (22L << 20));    // [1024,4096]   8 MB
    bf16* qkb  = (bf16*)(ws + (30L << 20));    // [4096,2048]  16 MB  (Q|K)
    bf16* vtb  = (bf16*)(ws + (46L << 20));    // [2,1024,2048] 8 MB  (V transposed)
    bf16* hbuf = (bf16*)(ws + (54L << 20));    // [4096,1024]   8 MB
    bf16* abuf = (bf16*)(ws + (62L << 20));    // [4096,4096]  32 MB

    auto cvt = [&](const float* s, bf16* d, int n) {
        cvt_f32_bf16<<<(n / 4 + 255) / 256, 256, 0, stream>>>(s, d, n);
    };
    cvt(x,  xb,              BT_ * D_);
    cvt(wq, wall,            D_ * D_);
    cvt(wk, wall + D_ * D_,  D_ * D_);
    cvt(wv, wall + 2 * D_ * D_, D_ * D_);
    cvt(w1, w1b, DFF_ * D_);
    cvt(w2, w2b, D_ * DFF_);

    // QKV projection: [4096,1024] x [3072,1024]^T -> qk [4096,2048] + vt [2][1024][2048]
    gemm_bt<3><<<dim3(3 * D_ / 128, BT_ / 128), 256, 0, stream>>>(
        xb, wall, qkb, vtb, nullptr, nullptr, BT_, 3 * D_, D_);

    // attention + residual: hbuf = x + attn_out
    attn_kernel<<<dim3(T_ / 64, H_, B_), 256, 0, stream>>>(qkb, vtb, x, hbuf);

    // FFN1: gelu(h @ w1^T + b1) -> [4096,4096] bf16
    gemm_bt<1><<<dim3(DFF_ / 128, BT_ / 128), 256, 0, stream>>>(
        hbuf, w1b, abuf, nullptr, b1, nullptr, BT_, DFF_, D_);

    // FFN2 + bias + residual x -> out fp32 [4096,1024]
    gemm_bt<2><<<dim3(D_ / 128, BT_ / 128), 256, 0, stream>>>(
        abuf, w2b, out, nullptr, b2, x, BT_, D_, DFF_);
}